// Round 9
// baseline (166.254 us; speedup 1.0000x reference)
//
#include <hip/hip_runtime.h>
#include <stdint.h>

#define NX 2048
#define NQ 512
#define CDIM 1024
#define NH 16
#define DH 64

typedef __attribute__((ext_vector_type(8))) __bf16 bf16x8;
typedef __attribute__((ext_vector_type(4))) float f32x4;

__device__ __forceinline__ uint16_t f2bf(float f) {
  uint32_t i = __float_as_uint(f);
  uint32_t r = i + 0x7fffu + ((i >> 16) & 1u);
  return (uint16_t)(r >> 16);
}

#define GLD16(g, l)                                                            \
  __builtin_amdgcn_global_load_lds(                                            \
      (const __attribute__((address_space(1))) uint32_t*)(g),                  \
      (__attribute__((address_space(3))) uint32_t*)(l), 16, 0, 0)

// ---------------- cast / transpose prep ----------------

__global__ __launch_bounds__(256) void cast_bf16_kernel(
    const float* __restrict__ src, uint16_t* __restrict__ dst, int n4) {
  int i = blockIdx.x * blockDim.x + threadIdx.x;
  int stride = gridDim.x * blockDim.x;
  for (; i < n4; i += stride) {
    float4 v = ((const float4*)src)[i];
    ushort4 o;
    o.x = f2bf(v.x); o.y = f2bf(v.y); o.z = f2bf(v.z); o.w = f2bf(v.w);
    ((ushort4*)dst)[i] = o;
  }
}

// src[K][N] fp32 (row-major) -> dst[N][K] bf16, LDS-tiled 64x64
__global__ __launch_bounds__(256) void transT_bf16_kernel(
    const float* __restrict__ src, uint16_t* __restrict__ dst, int K, int N) {
  __shared__ uint16_t tile[64][65];
  const int k0 = blockIdx.y * 64, n0 = blockIdx.x * 64;
  const int tid = threadIdx.x;
#pragma unroll
  for (int it = 0; it < 16; ++it) {
    int idx = it * 256 + tid;
    int r = idx >> 6, c = idx & 63;
    tile[r][c] = f2bf(src[(size_t)(k0 + r) * N + n0 + c]);
  }
  __syncthreads();
#pragma unroll
  for (int it = 0; it < 16; ++it) {
    int idx = it * 256 + tid;
    int r = idx >> 6, c = idx & 63;
    dst[(size_t)(n0 + r) * K + k0 + c] = tile[c][r];
  }
}

// ---------------- gate GEMV as MFMA: gv[b,h,nx] = xh[b,nx,:] . w_la[:,h] ----------------

__global__ __launch_bounds__(256) void gate_mm_kernel(
    const uint16_t* __restrict__ xh, const float* __restrict__ wla,
    float* __restrict__ gv) {
  __shared__ __align__(16) uint16_t sW[16 * 1024];  // 32 KB
  const int tid = threadIdx.x;
  const int wv = tid >> 6;
  const int lane = tid & 63;
  const int lr = lane & 15;
  const int lh = lane >> 4;

#pragma unroll
  for (int it = 0; it < 64; ++it) {
    int i = it * 256 + tid;
    int c = i >> 4, h = i & 15;
    sW[h * 1024 + (((c >> 3) ^ (h & 7)) << 3) + (c & 7)] = f2bf(wla[i]);
  }
  __syncthreads();

  const int rb = blockIdx.x * 64 + wv * 16;
  f32x4 acc = {0.f, 0.f, 0.f, 0.f};
  for (int t = 0; t < 32; ++t) {
    bf16x8 af = *(const bf16x8*)&xh[(size_t)(rb + lr) * 1024 + t * 32 + lh * 8];
    bf16x8 bf = *(const bf16x8*)&sW[lr * 1024 + (((t * 4 + lh) ^ (lr & 7)) << 3)];
    acc = __builtin_amdgcn_mfma_f32_16x16x32_bf16(af, bf, acc, 0, 0, 0);
  }
  int nxg = rb + lh * 4;
  int b = nxg >> 11, nx = nxg & 2047;
  float4 st = {acc[0], acc[1], acc[2], acc[3]};
  *(float4*)&gv[((size_t)b * NH + lr) * NX + nx] = st;
}

// ---------------- 8-phase 256x256 GEMM for x@w_kv ----------------
// (race-free stage schedule, see round-7 header comment)

__global__ __launch_bounds__(512, 2) void gemm_kv8(
    const uint16_t* __restrict__ A, const uint16_t* __restrict__ BT,
    uint16_t* __restrict__ outK, uint16_t* __restrict__ outV) {
  __shared__ __align__(16) uint16_t lds[65536];  // [buf][A|B][256][64]

  const int tid = threadIdx.x;
  const int wid = tid >> 6;
  const int lane = tid & 63;
  const int lr = lane & 15;
  const int lh = lane >> 4;
  const int wm = wid >> 2;
  const int wn = wid & 3;
  const int rowBase = blockIdx.x * 256;
  const int colBase = blockIdx.y * 256;

  f32x4 acc[8][4];
#pragma unroll
  for (int m = 0; m < 8; ++m)
#pragma unroll
    for (int n = 0; n < 4; ++n) acc[m][n] = (f32x4){0.f, 0.f, 0.f, 0.f};

  auto stageB = [&](int T, int h) {
    const uint16_t* srcp = BT + (size_t)(colBase + h * 128) * 1024 + T * 64;
    uint16_t* dst = lds + ((T & 1) * 32768 + 16384 + h * 8192);
#pragma unroll
    for (int it = 0; it < 2; ++it) {
      int s = it * 512 + tid;
      int row = s >> 3, cc = s & 7;
      int sc = cc ^ (row & 7);
      GLD16(srcp + (size_t)row * 1024 + sc * 8,
            dst + ((size_t)it * 512 + wid * 64) * 8);
    }
  };
  auto stageA012 = [&](int T) {
    const uint16_t* srcp = A + (size_t)rowBase * 1024 + T * 64;
    uint16_t* dstbase = lds + (T & 1) * 32768;
    int r64 = tid >> 3, cc = tid & 7;
#pragma unroll
    for (int st = 0; st < 3; ++st) {
      int rloc = (r64 < 32) ? (st * 32 + r64) : (96 + st * 32 + r64);
      int sc = cc ^ (rloc & 7);
      int wrow = (wid < 4) ? (st * 32 + wid * 8) : (128 + st * 32 + (wid - 4) * 8);
      GLD16(srcp + (size_t)rloc * 1024 + sc * 8, dstbase + (size_t)wrow * 64);
    }
  };
  auto stageA3 = [&](int T) {
    const uint16_t* srcp = A + (size_t)rowBase * 1024 + T * 64;
    uint16_t* dstbase = lds + (T & 1) * 32768;
    int r64 = tid >> 3, cc = tid & 7;
    int rloc = (r64 < 32) ? (96 + r64) : (192 + r64);
    int sc = cc ^ (rloc & 7);
    int wrow = (wid < 4) ? (96 + wid * 8) : (224 + (wid - 4) * 8);
    GLD16(srcp + (size_t)rloc * 1024 + sc * 8, dstbase + (size_t)wrow * 64);
  };

  auto rdA = [&](int p, int m, int kk) -> bf16x8 {
    int r = wm * 128 + m * 16 + lr;
    return *(const bf16x8*)&lds[p * 32768 + r * 64 +
                                (((kk * 4 + lh) ^ (r & 7)) << 3)];
  };
  auto rdB = [&](int p, int n, int kk) -> bf16x8 {
    int r = wn * 64 + n * 16 + lr;
    return *(const bf16x8*)&lds[p * 32768 + 16384 + r * 64 +
                                (((kk * 4 + lh) ^ (r & 7)) << 3)];
  };

  auto tile4 = [&](int t, bool last) {
    const int p = t & 1;
    bf16x8 b[4][2], a0[2], a1[2];
#pragma unroll
    for (int q = 0; q < 4; ++q) {
      if (q == 0) {
#pragma unroll
        for (int n = 0; n < 4; ++n)
#pragma unroll
          for (int kk = 0; kk < 2; ++kk) b[n][kk] = rdB(p, n, kk);
      }
#pragma unroll
      for (int kk = 0; kk < 2; ++kk) {
        a0[kk] = rdA(p, 2 * q, kk);
        a1[kk] = rdA(p, 2 * q + 1, kk);
      }
      if (q == 0) {
        stageA3(t + 1);
      } else if (q == 1) {
        if (!last) stageB(t + 2, 0);
      } else if (q == 2) {
        if (!last) stageB(t + 2, 1);
      } else {
        if (!last) stageA012(t + 2);
        if (last)
          asm volatile("s_waitcnt vmcnt(0)" ::: "memory");
        else
          asm volatile("s_waitcnt vmcnt(7)" ::: "memory");
      }
      __builtin_amdgcn_s_barrier();
      asm volatile("s_waitcnt lgkmcnt(0)" ::: "memory");
      __builtin_amdgcn_sched_barrier(0);
      __builtin_amdgcn_s_setprio(1);
#pragma unroll
      for (int n = 0; n < 4; ++n)
#pragma unroll
        for (int kk = 0; kk < 2; ++kk) {
          acc[2 * q][n] = __builtin_amdgcn_mfma_f32_16x16x32_bf16(
              a0[kk], b[n][kk], acc[2 * q][n], 0, 0, 0);
          acc[2 * q + 1][n] = __builtin_amdgcn_mfma_f32_16x16x32_bf16(
              a1[kk], b[n][kk], acc[2 * q + 1][n], 0, 0, 0);
        }
      __builtin_amdgcn_s_setprio(0);
      __builtin_amdgcn_s_barrier();
      asm volatile("" ::: "memory");
    }
  };

  auto tileEpi = [&](int t) {
    const int p = t & 1;
    bf16x8 b[4][2], a0[2], a1[2];
#pragma unroll
    for (int n = 0; n < 4; ++n)
#pragma unroll
      for (int kk = 0; kk < 2; ++kk) b[n][kk] = rdB(p, n, kk);
#pragma unroll
    for (int q = 0; q < 4; ++q) {
#pragma unroll
      for (int kk = 0; kk < 2; ++kk) {
        a0[kk] = rdA(p, 2 * q, kk);
        a1[kk] = rdA(p, 2 * q + 1, kk);
      }
#pragma unroll
      for (int n = 0; n < 4; ++n)
#pragma unroll
        for (int kk = 0; kk < 2; ++kk) {
          acc[2 * q][n] = __builtin_amdgcn_mfma_f32_16x16x32_bf16(
              a0[kk], b[n][kk], acc[2 * q][n], 0, 0, 0);
          acc[2 * q + 1][n] = __builtin_amdgcn_mfma_f32_16x16x32_bf16(
              a1[kk], b[n][kk], acc[2 * q + 1][n], 0, 0, 0);
        }
    }
  };

  stageB(0, 0); stageB(0, 1); stageA012(0); stageA3(0);
  stageB(1, 0); stageB(1, 1); stageA012(1);
  asm volatile("s_waitcnt vmcnt(7)" ::: "memory");
  __builtin_amdgcn_s_barrier();

  for (int t = 0; t < 14; ++t) tile4(t, false);
  tile4(14, true);
  tileEpi(15);

#pragma unroll
  for (int m = 0; m < 8; ++m) {
    int gr0 = rowBase + wm * 128 + m * 16 + lh * 4;
    int b_ = gr0 >> 11, nx0 = gr0 & 2047;
#pragma unroll
    for (int n = 0; n < 4; ++n) {
      int gc = colBase + wn * 64 + n * 16 + lr;
      if (gc < 1024) {
        int hh = gc >> 6, d = gc & 63;
        size_t base = (((size_t)b_ * NH + hh) * NX + nx0) * DH + d;
#pragma unroll
        for (int j = 0; j < 4; ++j)
          outK[base + (size_t)j * DH] = f2bf(acc[m][n][j]);
      } else {
        int c2 = gc - 1024;
        int hh = c2 >> 6, d = c2 & 63;
        ushort4 pv;
        pv.x = f2bf(acc[m][n][0]);
        pv.y = f2bf(acc[m][n][1]);
        pv.z = f2bf(acc[m][n][2]);
        pv.w = f2bf(acc[m][n][3]);
        *(ushort4*)&outV[(((size_t)b_ * NH + hh) * DH + d) * NX + nx0] = pv;
      }
    }
  }
}

// ---------------- 128x128 GEMM (A row-major bf16, B^T row-major bf16), K=1024 ----------------

template <int MODE>
__global__ __launch_bounds__(256) void gemm_bt(
    const uint16_t* __restrict__ A, const uint16_t* __restrict__ BT,
    uint16_t* __restrict__ outA, uint16_t* __restrict__ outB,
    float* __restrict__ outF, const float* __restrict__ bias) {
  constexpr int K = 1024;
  __shared__ __align__(16) uint16_t sA[128 * 32];
  __shared__ __align__(16) uint16_t sB[128 * 32];

  const int tid = threadIdx.x;
  const int wv = tid >> 6;
  const int lane = tid & 63;
  const int lr = lane & 15;
  const int lh = lane >> 4;
  const int wm = wv >> 1, wn = wv & 1;
  const int rowBase = blockIdx.x * 128;
  const int colBase = blockIdx.y * 128;

  f32x4 zero4 = {0.f, 0.f, 0.f, 0.f};
  f32x4 acc[4][4];
#pragma unroll
  for (int m = 0; m < 4; ++m)
#pragma unroll
    for (int n = 0; n < 4; ++n) acc[m][n] = zero4;

  for (int k0 = 0; k0 < K; k0 += 32) {
#pragma unroll
    for (int it = 0; it < 2; ++it) {
      int s = it * 256 + tid;
      int row = s >> 2, cc = s & 3;
      int sc = cc ^ ((row >> 1) & 3);
      GLD16(A + (size_t)(rowBase + row) * K + k0 + sc * 8,
            sA + ((size_t)it * 256 + wv * 64) * 8);
      GLD16(BT + (size_t)(colBase + row) * K + k0 + sc * 8,
            sB + ((size_t)it * 256 + wv * 64) * 8);
    }
    __syncthreads();
    bf16x8 af[4], bfr[4];
#pragma unroll
    for (int m = 0; m < 4; ++m) {
      int r = wm * 64 + m * 16 + lr;
      af[m] = *(const bf16x8*)&sA[r * 32 + ((lh ^ ((r >> 1) & 3)) << 3)];
    }
#pragma unroll
    for (int n = 0; n < 4; ++n) {
      int r = wn * 64 + n * 16 + lr;
      bfr[n] = *(const bf16x8*)&sB[r * 32 + ((lh ^ ((r >> 1) & 3)) << 3)];
    }
#pragma unroll
    for (int m = 0; m < 4; ++m)
#pragma unroll
      for (int n = 0; n < 4; ++n)
        acc[m][n] = __builtin_amdgcn_mfma_f32_16x16x32_bf16(af[m], bfr[n],
                                                            acc[m][n], 0, 0, 0);
    __syncthreads();
  }

#pragma unroll
  for (int m = 0; m < 4; ++m) {
    int gr0 = rowBase + wm * 64 + m * 16 + lh * 4;
#pragma unroll
    for (int n = 0; n < 4; ++n) {
      int gc = colBase + wn * 64 + n * 16 + lr;
      if (MODE == 1) {
        int b = gr0 >> 9, nq0 = gr0 & 511;
        int hh = gc >> 6, d = gc & 63;
        size_t base = (((size_t)b * NH + hh) * NQ + nq0) * DH + d;
#pragma unroll
        for (int j = 0; j < 4; ++j)
          outA[base + (size_t)j * DH] = f2bf(acc[m][n][j] * 0.125f);
      } else {
        float bi = bias[gc];
#pragma unroll
        for (int j = 0; j < 4; ++j)
          outF[(size_t)(gr0 + j) * 1024 + gc] = acc[m][n][j] + bi;
      }
    }
  }
}

// ---------------- gate reduce ----------------

__global__ __launch_bounds__(256) void gate2_kernel(
    const float* __restrict__ gv, float* __restrict__ gate) {
  const int bh = blockIdx.x;
  const int tid = threadIdx.x;
  const float* p = gv + (size_t)bh * NX;
  float s = 0.f, mx = -1e30f;
  for (int i = tid; i < NX; i += 256) {
    float v = p[i];
    s += v;
    mx = fmaxf(mx, v);
  }
#pragma unroll
  for (int off = 1; off < 64; off <<= 1) {
    s += __shfl_xor(s, off, 64);
    mx = fmaxf(mx, __shfl_xor(mx, off, 64));
  }
  __shared__ float ss[4], sm[4];
  int wv = tid >> 6, lane = tid & 63;
  if (lane == 0) { ss[wv] = s; sm[wv] = mx; }
  __syncthreads();
  if (tid == 0) {
    float S = ss[0] + ss[1] + ss[2] + ss[3];
    float M = fmaxf(fmaxf(sm[0], sm[1]), fmaxf(sm[2], sm[3]));
    gate[bh] = 0.5f * (S / (float)NX) + 0.5f * M;
  }
}

// ---------------- column sum of V ----------------

__global__ __launch_bounds__(256) void vcolsum_kernel(
    const uint16_t* __restrict__ VT, float* __restrict__ vcs) {
  const int bh = blockIdx.x;
  const int wv = threadIdx.x >> 6, lane = threadIdx.x & 63;
#pragma unroll
  for (int dd = 0; dd < 16; ++dd) {
    int d = dd * 4 + wv;
    const uint16_t* row = VT + ((size_t)bh * DH + d) * NX;
    float s = 0.f;
#pragma unroll
    for (int i = 0; i < 4; ++i) {
      bf16x8 v = *(const bf16x8*)&row[(i * 64 + lane) * 8];
#pragma unroll
      for (int j = 0; j < 8; ++j) s += (float)v[j];
    }
#pragma unroll
    for (int off = 1; off < 64; off <<= 1) s += __shfl_xor(s, off, 64);
    if (lane == 0) vcs[bh * DH + d] = s;
  }
}

// ---------------- attention: single-pass flash, linearized softmax-2 ----------------
// Round-9: 32 q-rows/block (2 waves, 128 thr), 1024 blocks -> 4 blocks/CU
// (LDS 40 KB) for 2x the latency-hiding TLP. bh on blockIdx.x keeps the
// same-XCD K/V sharing (id % 8 == bh % 8). Math identical to round 5-8.

__global__ __launch_bounds__(128) void attn_kernel(
    const uint16_t* __restrict__ Q, const uint16_t* __restrict__ K,
    const uint16_t* __restrict__ VT, const float* __restrict__ gate,
    const float* __restrict__ attw, const float* __restrict__ vcs,
    uint16_t* __restrict__ ctxh) {
  __shared__ __align__(16) uint16_t sK[128 * 64];
  __shared__ __align__(16) uint16_t sV[64 * 128];
  __shared__ __align__(16) __bf16 sPe[32 * 128];

  const int tid = threadIdx.x;
  const int wv = tid >> 6;  // 0..1
  const int lane = tid & 63;
  const int lr = lane & 15;
  const int lh = lane >> 4;
  const int bh = blockIdx.x;
  const int q0 = blockIdx.y * 32;
  const float g = gate[bh];
  const float w = attw[0];

  const uint16_t* Qb = Q + ((size_t)bh * NQ + q0) * DH;
  const uint16_t* Kb = K + (size_t)bh * NX * DH;
  const uint16_t* Vb = VT + (size_t)bh * DH * NX;

  bf16x8 qa[2];
#pragma unroll
  for (int kk = 0; kk < 2; ++kk)
    qa[kk] = *(const bf16x8*)&Qb[(wv * 16 + lr) * DH + kk * 32 + lh * 8];

  float lp[4] = {0.f, 0.f, 0.f, 0.f};
  f32x4 zero4 = {0.f, 0.f, 0.f, 0.f};
  f32x4 accp[4];
#pragma unroll
  for (int d = 0; d < 4; ++d) accp[d] = zero4;

  for (int kt = 0; kt < 16; ++kt) {
#pragma unroll
    for (int it = 0; it < 8; ++it) {
      int s = it * 128 + tid;
      int row = s >> 3, cc = s & 7;
      int sc = cc ^ (row & 7);
      GLD16(Kb + (size_t)(kt * 128 + row) * DH + sc * 8,
            sK + ((size_t)it * 128 + wv * 64) * 8);
    }
#pragma unroll
    for (int it = 0; it < 8; ++it) {
      int s = it * 128 + tid;
      int row = s >> 4, cc = s & 15;
      int sc = cc ^ (row & 15);
      GLD16(Vb + (size_t)row * NX + kt * 128 + sc * 8,
            sV + ((size_t)it * 128 + wv * 64) * 8);
    }
    __syncthreads();
#pragma unroll
    for (int n = 0; n < 8; ++n) {
      f32x4 a4 = {0.f, 0.f, 0.f, 0.f};
      int r = n * 16 + lr;
#pragma unroll
      for (int kk = 0; kk < 2; ++kk) {
        bf16x8 kb = *(const bf16x8*)&sK[r * 64 + (((kk * 4 + lh) ^ (r & 7)) << 3)];
        a4 = __builtin_amdgcn_mfma_f32_16x16x32_bf16(qa[kk], kb, a4, 0, 0, 0);
      }
#pragma unroll
      for (int j = 0; j < 4; ++j) {
        float e = __expf(a4[j]);
        lp[j] += e;
        int qr = wv * 16 + lh * 4 + j;
        int key = n * 16 + lr;
        int idx = qr * 128 + ((((key >> 3) ^ (qr & 15))) << 3) + (key & 7);
        sPe[idx] = (__bf16)e;
      }
    }
    __syncthreads();
    const int prow = wv * 16 + lr;
#pragma unroll
    for (int kk = 0; kk < 4; ++kk) {
      int pidx = prow * 128 + (((kk * 4 + lh) ^ (prow & 15)) << 3);
      bf16x8 pe = *(const bf16x8*)&sPe[pidx];
#pragma unroll
      for (int df = 0; df < 4; ++df) {
        int vr = df * 16 + lr;
        bf16x8 vb = *(const bf16x8*)&sV[vr * 128 + (((kk * 4 + lh) ^ (vr & 15)) << 3)];
        accp[df] = __builtin_amdgcn_mfma_f32_16x16x32_bf16(pe, vb, accp[df], 0, 0, 0);
      }
    }
    __syncthreads();
  }
#pragma unroll
  for (int off = 1; off < 16; off <<= 1)
#pragma unroll
    for (int j = 0; j < 4; ++j) lp[j] += __shfl_xor(lp[j], off, 64);

  const int b = bh >> 4, h = bh & 15;
  const float c1 = w / ((float)NX + g);
  const float c2 = w * g / ((float)NX + g) + (1.f - w);
  float rl[4];
#pragma unroll
  for (int j = 0; j < 4; ++j) rl[j] = 1.f / lp[j];
#pragma unroll
  for (int df = 0; df < 4; ++df) {
    int d = df * 16 + lr;
    float cv = vcs[bh * DH + d];
#pragma unroll
    for (int j = 0; j < 4; ++j) {
      int qr = q0 + wv * 16 + lh * 4 + j;
      float p = accp[df][j] * rl[j];
      ctxh[(((size_t)b * NQ + qr) * NH + h) * DH + d] = f2bf(c1 * cv + c2 * p);
    }
  }
}

// ---------------- launch ----------------

extern "C" void kernel_launch(void* const* d_in, const int* in_sizes, int n_in,
                              void* d_out, int out_size, void* d_ws,
                              size_t ws_size, hipStream_t stream) {
  const float* x = (const float*)d_in[0];
  const float* cls = (const float*)d_in[1];
  const float* w_kv = (const float*)d_in[2];
  const float* w_q = (const float*)d_in[3];
  const float* w_la = (const float*)d_in[4];
  const float* w_proj = (const float*)d_in[5];
  const float* b_proj = (const float*)d_in[6];
  const float* att_w = (const float*)d_in[7];
  float* out = (float*)d_out;

  char* ws = (char*)d_ws;
  size_t off = 0;
  auto alloc = [&](size_t bytes) {
    void* p = ws + off;
    off += (bytes + 255) & ~(size_t)255;
    return p;
  };
  uint16_t* xh = (uint16_t*)alloc(4ull * NX * CDIM * 2);
  uint16_t* ch = (uint16_t*)alloc(4ull * NQ * CDIM * 2);
  uint16_t* wkvT = (uint16_t*)alloc(2048ull * 1024 * 2);
  uint16_t* wqT = (uint16_t*)alloc(1024ull * 1024 * 2);
  uint16_t* wpT = (uint16_t*)alloc(1024ull * 1024 * 2);
  uint16_t* kbf = (uint16_t*)alloc(4ull * NH * NX * DH * 2);
  uint16_t* vT = (uint16_t*)alloc(4ull * NH * DH * NX * 2);
  uint16_t* qbf = (uint16_t*)alloc(4ull * NH * NQ * DH * 2);
  float* gv = (float*)alloc(4ull * NH * NX * 4);
  float* gate = (float*)alloc(1024);
  float* vcs = (float*)alloc(4ull * NH * DH * 4);
  uint16_t* ctxh = (uint16_t*)alloc(4ull * NQ * CDIM * 2);

  cast_bf16_kernel<<<2048, 256, 0, stream>>>(x, xh, 4 * NX * CDIM / 4);
  cast_bf16_kernel<<<1024, 256, 0, stream>>>(cls, ch, 4 * NQ * CDIM / 4);
  transT_bf16_kernel<<<dim3(32, 16), 256, 0, stream>>>(w_kv, wkvT, 1024, 2048);
  transT_bf16_kernel<<<dim3(16, 16), 256, 0, stream>>>(w_q, wqT, 1024, 1024);
  transT_bf16_kernel<<<dim3(16, 16), 256, 0, stream>>>(w_proj, wpT, 1024, 1024);

  gate_mm_kernel<<<128, 256, 0, stream>>>(xh, w_la, gv);
  gemm_kv8<<<dim3(32, 8), 512, 0, stream>>>(xh, wkvT, kbf, vT);
  gemm_bt<1><<<dim3(16, 8), 256, 0, stream>>>(ch, wqT, qbf, nullptr, nullptr, nullptr);

  gate2_kernel<<<64, 256, 0, stream>>>(gv, gate);
  vcolsum_kernel<<<64, 256, 0, stream>>>(vT, vcs);

  attn_kernel<<<dim3(64, 16), 128, 0, stream>>>(qbf, kbf, vT, gate, att_w, vcs, ctxh);

  gemm_bt<2><<<dim3(16, 8), 256, 0, stream>>>(ctxh, wpT, nullptr, nullptr, out, b_proj);
}

// Round 10
// 157.770 us; speedup vs baseline: 1.0538x; 1.0538x over previous
//
#include <hip/hip_runtime.h>
#include <stdint.h>

#define NX 2048
#define NQ 512
#define CDIM 1024
#define NH 16
#define DH 64

typedef __attribute__((ext_vector_type(8))) __bf16 bf16x8;
typedef __attribute__((ext_vector_type(4))) float f32x4;

__device__ __forceinline__ uint16_t f2bf(float f) {
  uint32_t i = __float_as_uint(f);
  uint32_t r = i + 0x7fffu + ((i >> 16) & 1u);
  return (uint16_t)(r >> 16);
}

#define GLD16(g, l)                                                            \
  __builtin_amdgcn_global_load_lds(                                            \
      (const __attribute__((address_space(1))) uint32_t*)(g),                  \
      (__attribute__((address_space(3))) uint32_t*)(l), 16, 0, 0)

// ---------------- fused casts: x->xh and cls->ch in one launch ----------------

__global__ __launch_bounds__(256) void cast2_bf16_kernel(
    const float* __restrict__ s0, uint16_t* __restrict__ d0, int n40,
    const float* __restrict__ s1, uint16_t* __restrict__ d1, int n41) {
  int i = blockIdx.x * blockDim.x + threadIdx.x;
  int stride = gridDim.x * blockDim.x;
  int ntot = n40 + n41;
  for (; i < ntot; i += stride) {
    if (i < n40) {
      float4 v = ((const float4*)s0)[i];
      ushort4 o;
      o.x = f2bf(v.x); o.y = f2bf(v.y); o.z = f2bf(v.z); o.w = f2bf(v.w);
      ((ushort4*)d0)[i] = o;
    } else {
      float4 v = ((const float4*)s1)[i - n40];
      ushort4 o;
      o.x = f2bf(v.x); o.y = f2bf(v.y); o.z = f2bf(v.z); o.w = f2bf(v.w);
      ((ushort4*)d1)[i - n40] = o;
    }
  }
}

// ---------------- fused weight transposes: w_kv, w_q, w_proj in one launch ----------------
// src[K=1024][N] fp32 -> dst[N][1024] bf16, LDS-tiled 64x64, z selects the weight.

__global__ __launch_bounds__(256) void transT_all_kernel(
    const float* __restrict__ w_kv, uint16_t* __restrict__ wkvT,
    const float* __restrict__ w_q, uint16_t* __restrict__ wqT,
    const float* __restrict__ w_proj, uint16_t* __restrict__ wpT) {
  const int z = blockIdx.z;
  const float* src;
  uint16_t* dst;
  int N;
  if (z == 0) { src = w_kv; dst = wkvT; N = 2048; }
  else if (z == 1) { src = w_q; dst = wqT; N = 1024; }
  else { src = w_proj; dst = wpT; N = 1024; }
  const int n0 = blockIdx.x * 64;
  if (n0 >= N) return;
  const int k0 = blockIdx.y * 64;
  __shared__ uint16_t tile[64][65];
  const int tid = threadIdx.x;
#pragma unroll
  for (int it = 0; it < 16; ++it) {
    int idx = it * 256 + tid;
    int r = idx >> 6, c = idx & 63;
    tile[r][c] = f2bf(src[(size_t)(k0 + r) * N + n0 + c]);
  }
  __syncthreads();
#pragma unroll
  for (int it = 0; it < 16; ++it) {
    int idx = it * 256 + tid;
    int r = idx >> 6, c = idx & 63;
    dst[(size_t)(n0 + r) * 1024 + k0 + c] = tile[c][r];
  }
}

// ---------------- gate GEMV as MFMA: gv[b,h,nx] = xh[b,nx,:] . w_la[:,h] ----------------

__global__ __launch_bounds__(256) void gate_mm_kernel(
    const uint16_t* __restrict__ xh, const float* __restrict__ wla,
    float* __restrict__ gv) {
  __shared__ __align__(16) uint16_t sW[16 * 1024];  // 32 KB
  const int tid = threadIdx.x;
  const int wv = tid >> 6;
  const int lane = tid & 63;
  const int lr = lane & 15;
  const int lh = lane >> 4;

#pragma unroll
  for (int it = 0; it < 64; ++it) {
    int i = it * 256 + tid;
    int c = i >> 4, h = i & 15;
    sW[h * 1024 + (((c >> 3) ^ (h & 7)) << 3) + (c & 7)] = f2bf(wla[i]);
  }
  __syncthreads();

  const int rb = blockIdx.x * 64 + wv * 16;
  f32x4 acc = {0.f, 0.f, 0.f, 0.f};
  for (int t = 0; t < 32; ++t) {
    bf16x8 af = *(const bf16x8*)&xh[(size_t)(rb + lr) * 1024 + t * 32 + lh * 8];
    bf16x8 bf = *(const bf16x8*)&sW[lr * 1024 + (((t * 4 + lh) ^ (lr & 7)) << 3)];
    acc = __builtin_amdgcn_mfma_f32_16x16x32_bf16(af, bf, acc, 0, 0, 0);
  }
  int nxg = rb + lh * 4;
  int b = nxg >> 11, nx = nxg & 2047;
  float4 st = {acc[0], acc[1], acc[2], acc[3]};
  *(float4*)&gv[((size_t)b * NH + lr) * NX + nx] = st;
}

// ---------------- 8-phase 256x256 GEMM: x@w_kv (+ fused cls@w_q blocks) ----------------
// Blocks x<32: kv tiles C[8192][2048] (race-free schedule, round-7 header).
// Blocks x>=32, y<4: q-proj tiles cls[2048]@wqT -> q [B,H,N,D] *0.125.
// XCD map: id = x + 40*y, id%8 = x%8 -> A-panel (fixed x) shares an XCD for
// both block families. 40*y ≡ 0 mod 8.

__global__ __launch_bounds__(512, 2) void gemm_kv8q(
    const uint16_t* __restrict__ A, const uint16_t* __restrict__ BT,
    uint16_t* __restrict__ outK, uint16_t* __restrict__ outV,
    const uint16_t* __restrict__ Aq, const uint16_t* __restrict__ BTq,
    uint16_t* __restrict__ outQ) {
  __shared__ __align__(16) uint16_t lds[65536];  // [buf][A|B][256][64]

  const int bx = blockIdx.x, by = blockIdx.y;
  const bool isQ = bx >= 32;
  if (isQ && by >= 4) return;

  const uint16_t* Ap = isQ ? Aq : A;
  const uint16_t* BTp = isQ ? BTq : BT;
  const int rowBase = (isQ ? (bx - 32) : bx) * 256;
  const int colBase = by * 256;

  const int tid = threadIdx.x;
  const int wid = tid >> 6;
  const int lane = tid & 63;
  const int lr = lane & 15;
  const int lh = lane >> 4;
  const int wm = wid >> 2;
  const int wn = wid & 3;

  f32x4 acc[8][4];
#pragma unroll
  for (int m = 0; m < 8; ++m)
#pragma unroll
    for (int n = 0; n < 4; ++n) acc[m][n] = (f32x4){0.f, 0.f, 0.f, 0.f};

  auto stageB = [&](int T, int h) {
    const uint16_t* srcp = BTp + (size_t)(colBase + h * 128) * 1024 + T * 64;
    uint16_t* dst = lds + ((T & 1) * 32768 + 16384 + h * 8192);
#pragma unroll
    for (int it = 0; it < 2; ++it) {
      int s = it * 512 + tid;
      int row = s >> 3, cc = s & 7;
      int sc = cc ^ (row & 7);
      GLD16(srcp + (size_t)row * 1024 + sc * 8,
            dst + ((size_t)it * 512 + wid * 64) * 8);
    }
  };
  auto stageA012 = [&](int T) {
    const uint16_t* srcp = Ap + (size_t)rowBase * 1024 + T * 64;
    uint16_t* dstbase = lds + (T & 1) * 32768;
    int r64 = tid >> 3, cc = tid & 7;
#pragma unroll
    for (int st = 0; st < 3; ++st) {
      int rloc = (r64 < 32) ? (st * 32 + r64) : (96 + st * 32 + r64);
      int sc = cc ^ (rloc & 7);
      int wrow = (wid < 4) ? (st * 32 + wid * 8) : (128 + st * 32 + (wid - 4) * 8);
      GLD16(srcp + (size_t)rloc * 1024 + sc * 8, dstbase + (size_t)wrow * 64);
    }
  };
  auto stageA3 = [&](int T) {
    const uint16_t* srcp = Ap + (size_t)rowBase * 1024 + T * 64;
    uint16_t* dstbase = lds + (T & 1) * 32768;
    int r64 = tid >> 3, cc = tid & 7;
    int rloc = (r64 < 32) ? (96 + r64) : (192 + r64);
    int sc = cc ^ (rloc & 7);
    int wrow = (wid < 4) ? (96 + wid * 8) : (224 + (wid - 4) * 8);
    GLD16(srcp + (size_t)rloc * 1024 + sc * 8, dstbase + (size_t)wrow * 64);
  };

  auto rdA = [&](int p, int m, int kk) -> bf16x8 {
    int r = wm * 128 + m * 16 + lr;
    return *(const bf16x8*)&lds[p * 32768 + r * 64 +
                                (((kk * 4 + lh) ^ (r & 7)) << 3)];
  };
  auto rdB = [&](int p, int n, int kk) -> bf16x8 {
    int r = wn * 64 + n * 16 + lr;
    return *(const bf16x8*)&lds[p * 32768 + 16384 + r * 64 +
                                (((kk * 4 + lh) ^ (r & 7)) << 3)];
  };

  auto tile4 = [&](int t, bool last) {
    const int p = t & 1;
    bf16x8 b[4][2], a0[2], a1[2];
#pragma unroll
    for (int q = 0; q < 4; ++q) {
      if (q == 0) {
#pragma unroll
        for (int n = 0; n < 4; ++n)
#pragma unroll
          for (int kk = 0; kk < 2; ++kk) b[n][kk] = rdB(p, n, kk);
      }
#pragma unroll
      for (int kk = 0; kk < 2; ++kk) {
        a0[kk] = rdA(p, 2 * q, kk);
        a1[kk] = rdA(p, 2 * q + 1, kk);
      }
      if (q == 0) {
        stageA3(t + 1);
      } else if (q == 1) {
        if (!last) stageB(t + 2, 0);
      } else if (q == 2) {
        if (!last) stageB(t + 2, 1);
      } else {
        if (!last) stageA012(t + 2);
        if (last)
          asm volatile("s_waitcnt vmcnt(0)" ::: "memory");
        else
          asm volatile("s_waitcnt vmcnt(7)" ::: "memory");
      }
      __builtin_amdgcn_s_barrier();
      asm volatile("s_waitcnt lgkmcnt(0)" ::: "memory");
      __builtin_amdgcn_sched_barrier(0);
      __builtin_amdgcn_s_setprio(1);
#pragma unroll
      for (int n = 0; n < 4; ++n)
#pragma unroll
        for (int kk = 0; kk < 2; ++kk) {
          acc[2 * q][n] = __builtin_amdgcn_mfma_f32_16x16x32_bf16(
              a0[kk], b[n][kk], acc[2 * q][n], 0, 0, 0);
          acc[2 * q + 1][n] = __builtin_amdgcn_mfma_f32_16x16x32_bf16(
              a1[kk], b[n][kk], acc[2 * q + 1][n], 0, 0, 0);
        }
      __builtin_amdgcn_s_setprio(0);
      __builtin_amdgcn_s_barrier();
      asm volatile("" ::: "memory");
    }
  };

  auto tileEpi = [&](int t) {
    const int p = t & 1;
    bf16x8 b[4][2], a0[2], a1[2];
#pragma unroll
    for (int n = 0; n < 4; ++n)
#pragma unroll
      for (int kk = 0; kk < 2; ++kk) b[n][kk] = rdB(p, n, kk);
#pragma unroll
    for (int q = 0; q < 4; ++q) {
#pragma unroll
      for (int kk = 0; kk < 2; ++kk) {
        a0[kk] = rdA(p, 2 * q, kk);
        a1[kk] = rdA(p, 2 * q + 1, kk);
      }
#pragma unroll
      for (int n = 0; n < 4; ++n)
#pragma unroll
        for (int kk = 0; kk < 2; ++kk) {
          acc[2 * q][n] = __builtin_amdgcn_mfma_f32_16x16x32_bf16(
              a0[kk], b[n][kk], acc[2 * q][n], 0, 0, 0);
          acc[2 * q + 1][n] = __builtin_amdgcn_mfma_f32_16x16x32_bf16(
              a1[kk], b[n][kk], acc[2 * q + 1][n], 0, 0, 0);
        }
    }
  };

  stageB(0, 0); stageB(0, 1); stageA012(0); stageA3(0);
  stageB(1, 0); stageB(1, 1); stageA012(1);
  asm volatile("s_waitcnt vmcnt(7)" ::: "memory");
  __builtin_amdgcn_s_barrier();

  for (int t = 0; t < 14; ++t) tile4(t, false);
  tile4(14, true);
  tileEpi(15);

  if (isQ) {
    // q-proj epilogue: outQ[b,h,nq,d] = acc * 0.125 (rows in [0,2048))
#pragma unroll
    for (int m = 0; m < 8; ++m) {
      int gr0 = rowBase + wm * 128 + m * 16 + lh * 4;
      int b_ = gr0 >> 9, nq0 = gr0 & 511;
#pragma unroll
      for (int n = 0; n < 4; ++n) {
        int gc = colBase + wn * 64 + n * 16 + lr;
        int hh = gc >> 6, d = gc & 63;
        size_t base = (((size_t)b_ * NH + hh) * NQ + nq0) * DH + d;
#pragma unroll
        for (int j = 0; j < 4; ++j)
          outQ[base + (size_t)j * DH] = f2bf(acc[m][n][j] * 0.125f);
      }
    }
  } else {
#pragma unroll
    for (int m = 0; m < 8; ++m) {
      int gr0 = rowBase + wm * 128 + m * 16 + lh * 4;
      int b_ = gr0 >> 11, nx0 = gr0 & 2047;
#pragma unroll
      for (int n = 0; n < 4; ++n) {
        int gc = colBase + wn * 64 + n * 16 + lr;
        if (gc < 1024) {
          int hh = gc >> 6, d = gc & 63;
          size_t base = (((size_t)b_ * NH + hh) * NX + nx0) * DH + d;
#pragma unroll
          for (int j = 0; j < 4; ++j)
            outK[base + (size_t)j * DH] = f2bf(acc[m][n][j]);
        } else {
          int c2 = gc - 1024;
          int hh = c2 >> 6, d = c2 & 63;
          ushort4 pv;
          pv.x = f2bf(acc[m][n][0]);
          pv.y = f2bf(acc[m][n][1]);
          pv.z = f2bf(acc[m][n][2]);
          pv.w = f2bf(acc[m][n][3]);
          *(ushort4*)&outV[(((size_t)b_ * NH + hh) * DH + d) * NX + nx0] = pv;
        }
      }
    }
  }
}

// ---------------- 128x128 GEMM, MODE 2 only: ctx@w_proj + bias -> out fp32 ----------------

__global__ __launch_bounds__(256) void gemm_proj(
    const uint16_t* __restrict__ A, const uint16_t* __restrict__ BT,
    float* __restrict__ outF, const float* __restrict__ bias) {
  constexpr int K = 1024;
  __shared__ __align__(16) uint16_t sA[128 * 32];
  __shared__ __align__(16) uint16_t sB[128 * 32];

  const int tid = threadIdx.x;
  const int wv = tid >> 6;
  const int lane = tid & 63;
  const int lr = lane & 15;
  const int lh = lane >> 4;
  const int wm = wv >> 1, wn = wv & 1;
  const int rowBase = blockIdx.x * 128;
  const int colBase = blockIdx.y * 128;

  f32x4 zero4 = {0.f, 0.f, 0.f, 0.f};
  f32x4 acc[4][4];
#pragma unroll
  for (int m = 0; m < 4; ++m)
#pragma unroll
    for (int n = 0; n < 4; ++n) acc[m][n] = zero4;

  for (int k0 = 0; k0 < K; k0 += 32) {
#pragma unroll
    for (int it = 0; it < 2; ++it) {
      int s = it * 256 + tid;
      int row = s >> 2, cc = s & 3;
      int sc = cc ^ ((row >> 1) & 3);
      GLD16(A + (size_t)(rowBase + row) * K + k0 + sc * 8,
            sA + ((size_t)it * 256 + wv * 64) * 8);
      GLD16(BT + (size_t)(colBase + row) * K + k0 + sc * 8,
            sB + ((size_t)it * 256 + wv * 64) * 8);
    }
    __syncthreads();
    bf16x8 af[4], bfr[4];
#pragma unroll
    for (int m = 0; m < 4; ++m) {
      int r = wm * 64 + m * 16 + lr;
      af[m] = *(const bf16x8*)&sA[r * 32 + ((lh ^ ((r >> 1) & 3)) << 3)];
    }
#pragma unroll
    for (int n = 0; n < 4; ++n) {
      int r = wn * 64 + n * 16 + lr;
      bfr[n] = *(const bf16x8*)&sB[r * 32 + ((lh ^ ((r >> 1) & 3)) << 3)];
    }
#pragma unroll
    for (int m = 0; m < 4; ++m)
#pragma unroll
      for (int n = 0; n < 4; ++n)
        acc[m][n] = __builtin_amdgcn_mfma_f32_16x16x32_bf16(af[m], bfr[n],
                                                            acc[m][n], 0, 0, 0);
    __syncthreads();
  }

#pragma unroll
  for (int m = 0; m < 4; ++m) {
    int gr0 = rowBase + wm * 64 + m * 16 + lh * 4;
#pragma unroll
    for (int n = 0; n < 4; ++n) {
      int gc = colBase + wn * 64 + n * 16 + lr;
      float bi = bias[gc];
#pragma unroll
      for (int j = 0; j < 4; ++j)
        outF[(size_t)(gr0 + j) * 1024 + gc] = acc[m][n][j] + bi;
    }
  }
}

// ---------------- gate reduce ----------------

__global__ __launch_bounds__(256) void gate2_kernel(
    const float* __restrict__ gv, float* __restrict__ gate) {
  const int bh = blockIdx.x;
  const int tid = threadIdx.x;
  const float* p = gv + (size_t)bh * NX;
  float s = 0.f, mx = -1e30f;
  for (int i = tid; i < NX; i += 256) {
    float v = p[i];
    s += v;
    mx = fmaxf(mx, v);
  }
#pragma unroll
  for (int off = 1; off < 64; off <<= 1) {
    s += __shfl_xor(s, off, 64);
    mx = fmaxf(mx, __shfl_xor(mx, off, 64));
  }
  __shared__ float ss[4], sm[4];
  int wv = tid >> 6, lane = tid & 63;
  if (lane == 0) { ss[wv] = s; sm[wv] = mx; }
  __syncthreads();
  if (tid == 0) {
    float S = ss[0] + ss[1] + ss[2] + ss[3];
    float M = fmaxf(fmaxf(sm[0], sm[1]), fmaxf(sm[2], sm[3]));
    gate[bh] = 0.5f * (S / (float)NX) + 0.5f * M;
  }
}

// ---------------- column sum of V (grid 64x4: 4x the blocks of round 8) ----------------

__global__ __launch_bounds__(256) void vcolsum_kernel(
    const uint16_t* __restrict__ VT, float* __restrict__ vcs) {
  const int bh = blockIdx.x;
  const int wv = threadIdx.x >> 6, lane = threadIdx.x & 63;
#pragma unroll
  for (int dd = 0; dd < 4; ++dd) {
    int d = blockIdx.y * 16 + dd * 4 + wv;
    const uint16_t* row = VT + ((size_t)bh * DH + d) * NX;
    float s = 0.f;
#pragma unroll
    for (int i = 0; i < 4; ++i) {
      bf16x8 v = *(const bf16x8*)&row[(i * 64 + lane) * 8];
#pragma unroll
      for (int j = 0; j < 8; ++j) s += (float)v[j];
    }
#pragma unroll
    for (int off = 1; off < 64; off <<= 1) s += __shfl_xor(s, off, 64);
    if (lane == 0) vcs[bh * DH + d] = s;
  }
}

// ---------------- attention: single-pass flash, linearized softmax-2 (round-8 proven) ----------------

__global__ __launch_bounds__(256) void attn_kernel(
    const uint16_t* __restrict__ Q, const uint16_t* __restrict__ K,
    const uint16_t* __restrict__ VT, const float* __restrict__ gate,
    const float* __restrict__ attw, const float* __restrict__ vcs,
    uint16_t* __restrict__ ctxh) {
  __shared__ __align__(16) uint16_t sK[128 * 64];
  __shared__ __align__(16) uint16_t sV[64 * 128];
  __shared__ __align__(16) __bf16 sPe[64 * 128];

  const int tid = threadIdx.x;
  const int wv = tid >> 6;
  const int lane = tid & 63;
  const int lr = lane & 15;
  const int lh = lane >> 4;
  const int bh = blockIdx.x;
  const int q0 = blockIdx.y * 64;
  const float g = gate[bh];
  const float w = attw[0];

  const uint16_t* Qb = Q + ((size_t)bh * NQ + q0) * DH;
  const uint16_t* Kb = K + (size_t)bh * NX * DH;
  const uint16_t* Vb = VT + (size_t)bh * DH * NX;

  bf16x8 qa[2];
#pragma unroll
  for (int kk = 0; kk < 2; ++kk)
    qa[kk] = *(const bf16x8*)&Qb[(wv * 16 + lr) * DH + kk * 32 + lh * 8];

  float lp[4] = {0.f, 0.f, 0.f, 0.f};
  f32x4 zero4 = {0.f, 0.f, 0.f, 0.f};
  f32x4 accp[4];
#pragma unroll
  for (int d = 0; d < 4; ++d) accp[d] = zero4;

  for (int kt = 0; kt < 16; ++kt) {
#pragma unroll
    for (int it = 0; it < 4; ++it) {
      int s = it * 256 + tid;
      int row = s >> 3, cc = s & 7;
      int sc = cc ^ (row & 7);
      GLD16(Kb + (size_t)(kt * 128 + row) * DH + sc * 8,
            sK + ((size_t)it * 256 + wv * 64) * 8);
    }
#pragma unroll
    for (int it = 0; it < 4; ++it) {
      int s = it * 256 + tid;
      int row = s >> 4, cc = s & 15;
      int sc = cc ^ (row & 15);
      GLD16(Vb + (size_t)row * NX + kt * 128 + sc * 8,
            sV + ((size_t)it * 256 + wv * 64) * 8);
    }
    __syncthreads();
#pragma unroll
    for (int n = 0; n < 8; ++n) {
      f32x4 a4 = {0.f, 0.f, 0.f, 0.f};
      int r = n * 16 + lr;
#pragma unroll
      for (int kk = 0; kk < 2; ++kk) {
        bf16x8 kb = *(const bf16x8*)&sK[r * 64 + (((kk * 4 + lh) ^ (r & 7)) << 3)];
        a4 = __builtin_amdgcn_mfma_f32_16x16x32_bf16(qa[kk], kb, a4, 0, 0, 0);
      }
#pragma unroll
      for (int j = 0; j < 4; ++j) {
        float e = __expf(a4[j]);
        lp[j] += e;
        int qr = wv * 16 + lh * 4 + j;
        int key = n * 16 + lr;
        int idx = qr * 128 + ((((key >> 3) ^ (qr & 15))) << 3) + (key & 7);
        sPe[idx] = (__bf16)e;
      }
    }
    __syncthreads();
    const int prow = wv * 16 + lr;
#pragma unroll
    for (int kk = 0; kk < 4; ++kk) {
      int pidx = prow * 128 + (((kk * 4 + lh) ^ (prow & 15)) << 3);
      bf16x8 pe = *(const bf16x8*)&sPe[pidx];
#pragma unroll
      for (int df = 0; df < 4; ++df) {
        int vr = df * 16 + lr;
        bf16x8 vb = *(const bf16x8*)&sV[vr * 128 + (((kk * 4 + lh) ^ (vr & 15)) << 3)];
        accp[df] = __builtin_amdgcn_mfma_f32_16x16x32_bf16(pe, vb, accp[df], 0, 0, 0);
      }
    }
    __syncthreads();
  }
#pragma unroll
  for (int off = 1; off < 16; off <<= 1)
#pragma unroll
    for (int j = 0; j < 4; ++j) lp[j] += __shfl_xor(lp[j], off, 64);

  const int b = bh >> 4, h = bh & 15;
  const float c1 = w / ((float)NX + g);
  const float c2 = w * g / ((float)NX + g) + (1.f - w);
  float rl[4];
#pragma unroll
  for (int j = 0; j < 4; ++j) rl[j] = 1.f / lp[j];
#pragma unroll
  for (int df = 0; df < 4; ++df) {
    int d = df * 16 + lr;
    float cv = vcs[bh * DH + d];
#pragma unroll
    for (int j = 0; j < 4; ++j) {
      int qr = q0 + wv * 16 + lh * 4 + j;
      float p = accp[df][j] * rl[j];
      ctxh[(((size_t)b * NQ + qr) * NH + h) * DH + d] = f2bf(c1 * cv + c2 * p);
    }
  }
}

// ---------------- launch ----------------

extern "C" void kernel_launch(void* const* d_in, const int* in_sizes, int n_in,
                              void* d_out, int out_size, void* d_ws,
                              size_t ws_size, hipStream_t stream) {
  const float* x = (const float*)d_in[0];
  const float* cls = (const float*)d_in[1];
  const float* w_kv = (const float*)d_in[2];
  const float* w_q = (const float*)d_in[3];
  const float* w_la = (const float*)d_in[4];
  const float* w_proj = (const float*)d_in[5];
  const float* b_proj = (const float*)d_in[6];
  const float* att_w = (const float*)d_in[7];
  float* out = (float*)d_out;

  char* ws = (char*)d_ws;
  size_t off = 0;
  auto alloc = [&](size_t bytes) {
    void* p = ws + off;
    off += (bytes + 255) & ~(size_t)255;
    return p;
  };
  uint16_t* xh = (uint16_t*)alloc(4ull * NX * CDIM * 2);
  uint16_t* ch = (uint16_t*)alloc(4ull * NQ * CDIM * 2);
  uint16_t* wkvT = (uint16_t*)alloc(2048ull * 1024 * 2);
  uint16_t* wqT = (uint16_t*)alloc(1024ull * 1024 * 2);
  uint16_t* wpT = (uint16_t*)alloc(1024ull * 1024 * 2);
  uint16_t* kbf = (uint16_t*)alloc(4ull * NH * NX * DH * 2);
  uint16_t* vT = (uint16_t*)alloc(4ull * NH * DH * NX * 2);
  uint16_t* qbf = (uint16_t*)alloc(4ull * NH * NQ * DH * 2);
  float* gv = (float*)alloc(4ull * NH * NX * 4);
  float* gate = (float*)alloc(1024);
  float* vcs = (float*)alloc(4ull * NH * DH * 4);
  uint16_t* ctxh = (uint16_t*)alloc(4ull * NQ * CDIM * 2);

  cast2_bf16_kernel<<<2048, 256, 0, stream>>>(x, xh, 4 * NX * CDIM / 4,
                                              cls, ch, 4 * NQ * CDIM / 4);
  transT_all_kernel<<<dim3(32, 16, 3), 256, 0, stream>>>(w_kv, wkvT, w_q, wqT,
                                                         w_proj, wpT);

  gate_mm_kernel<<<128, 256, 0, stream>>>(xh, w_la, gv);
  gemm_kv8q<<<dim3(40, 8), 512, 0, stream>>>(xh, wkvT, kbf, vT, ch, wqT, qbf);

  gate2_kernel<<<64, 256, 0, stream>>>(gv, gate);
  vcolsum_kernel<<<dim3(64, 4), 256, 0, stream>>>(vT, vcs);

  attn_kernel<<<dim3(64, 8), 256, 0, stream>>>(qbf, kbf, vT, gate, att_w, vcs, ctxh);

  gemm_proj<<<dim3(16, 8), 256, 0, stream>>>(ctxh, wpT, out, b_proj);
}

// Round 11
// 142.690 us; speedup vs baseline: 1.1651x; 1.1057x over previous
//
#include <hip/hip_runtime.h>
#include <stdint.h>

#define NX 2048
#define NQ 512
#define CDIM 1024
#define NH 16
#define DH 64

typedef __attribute__((ext_vector_type(8))) __bf16 bf16x8;
typedef __attribute__((ext_vector_type(4))) float f32x4;

__device__ __forceinline__ uint16_t f2bf(float f) {
  uint32_t i = __float_as_uint(f);
  uint32_t r = i + 0x7fffu + ((i >> 16) & 1u);
  return (uint16_t)(r >> 16);
}

#define GLD16(g, l)                                                            \
  __builtin_amdgcn_global_load_lds(                                            \
      (const __attribute__((address_space(1))) uint32_t*)(g),                  \
      (__attribute__((address_space(3))) uint32_t*)(l), 16, 0, 0)

// ---------------- fused casts: x->xh and cls->ch in one launch ----------------

__global__ __launch_bounds__(256) void cast2_bf16_kernel(
    const float* __restrict__ s0, uint16_t* __restrict__ d0, int n40,
    const float* __restrict__ s1, uint16_t* __restrict__ d1, int n41) {
  int i = blockIdx.x * blockDim.x + threadIdx.x;
  int stride = gridDim.x * blockDim.x;
  int ntot = n40 + n41;
  for (; i < ntot; i += stride) {
    if (i < n40) {
      float4 v = ((const float4*)s0)[i];
      ushort4 o;
      o.x = f2bf(v.x); o.y = f2bf(v.y); o.z = f2bf(v.z); o.w = f2bf(v.w);
      ((ushort4*)d0)[i] = o;
    } else {
      float4 v = ((const float4*)s1)[i - n40];
      ushort4 o;
      o.x = f2bf(v.x); o.y = f2bf(v.y); o.z = f2bf(v.z); o.w = f2bf(v.w);
      ((ushort4*)d1)[i - n40] = o;
    }
  }
}

// ---------------- fused weight transposes: w_kv, w_q, w_proj in one launch ----------------

__global__ __launch_bounds__(256) void transT_all_kernel(
    const float* __restrict__ w_kv, uint16_t* __restrict__ wkvT,
    const float* __restrict__ w_q, uint16_t* __restrict__ wqT,
    const float* __restrict__ w_proj, uint16_t* __restrict__ wpT) {
  const int z = blockIdx.z;
  const float* src;
  uint16_t* dst;
  int N;
  if (z == 0) { src = w_kv; dst = wkvT; N = 2048; }
  else if (z == 1) { src = w_q; dst = wqT; N = 1024; }
  else { src = w_proj; dst = wpT; N = 1024; }
  const int n0 = blockIdx.x * 64;
  if (n0 >= N) return;
  const int k0 = blockIdx.y * 64;
  __shared__ uint16_t tile[64][65];
  const int tid = threadIdx.x;
#pragma unroll
  for (int it = 0; it < 16; ++it) {
    int idx = it * 256 + tid;
    int r = idx >> 6, c = idx & 63;
    tile[r][c] = f2bf(src[(size_t)(k0 + r) * N + n0 + c]);
  }
  __syncthreads();
#pragma unroll
  for (int it = 0; it < 16; ++it) {
    int idx = it * 256 + tid;
    int r = idx >> 6, c = idx & 63;
    dst[(size_t)(n0 + r) * 1024 + k0 + c] = tile[c][r];
  }
}

// ---------------- aux_mm: q-proj (blocks 0..127) + gate GEMV (blocks 128..255) ----------------
// One 256-block launch = full CU fill, no tail. Both bodies are the proven
// round-8/10 kernels verbatim; 32 KB LDS union.

__global__ __launch_bounds__(256) void aux_mm_kernel(
    const uint16_t* __restrict__ ch, const uint16_t* __restrict__ wqT,
    uint16_t* __restrict__ qbf, const uint16_t* __restrict__ xh,
    const float* __restrict__ wla, float* __restrict__ gv) {
  __shared__ __align__(16) uint16_t smem[16 * 1024];  // 32 KB union
  const int tid = threadIdx.x;
  const int wv = tid >> 6;
  const int lane = tid & 63;
  const int lr = lane & 15;
  const int lh = lane >> 4;

  if (blockIdx.x < 128) {
    // ---- q-proj: cls@wqT -> q [B,H,N,D] * 0.125, 128x128 tile ----
    uint16_t* sA = smem;                 // 128*32
    uint16_t* sB = smem + 128 * 32;      // 128*32
    const int wm = wv >> 1, wn = wv & 1;
    const int rowBase = (blockIdx.x & 15) * 128;   // rt: A-panel fixed mod 8 -> same XCD
    const int colBase = (blockIdx.x >> 4) * 128;

    f32x4 zero4 = {0.f, 0.f, 0.f, 0.f};
    f32x4 acc[4][4];
#pragma unroll
    for (int m = 0; m < 4; ++m)
#pragma unroll
      for (int n = 0; n < 4; ++n) acc[m][n] = zero4;

    for (int k0 = 0; k0 < 1024; k0 += 32) {
#pragma unroll
      for (int it = 0; it < 2; ++it) {
        int s = it * 256 + tid;
        int row = s >> 2, cc = s & 3;
        int sc = cc ^ ((row >> 1) & 3);
        GLD16(ch + (size_t)(rowBase + row) * 1024 + k0 + sc * 8,
              sA + ((size_t)it * 256 + wv * 64) * 8);
        GLD16(wqT + (size_t)(colBase + row) * 1024 + k0 + sc * 8,
              sB + ((size_t)it * 256 + wv * 64) * 8);
      }
      __syncthreads();
      bf16x8 af[4], bfr[4];
#pragma unroll
      for (int m = 0; m < 4; ++m) {
        int r = wm * 64 + m * 16 + lr;
        af[m] = *(const bf16x8*)&sA[r * 32 + ((lh ^ ((r >> 1) & 3)) << 3)];
      }
#pragma unroll
      for (int n = 0; n < 4; ++n) {
        int r = wn * 64 + n * 16 + lr;
        bfr[n] = *(const bf16x8*)&sB[r * 32 + ((lh ^ ((r >> 1) & 3)) << 3)];
      }
#pragma unroll
      for (int m = 0; m < 4; ++m)
#pragma unroll
        for (int n = 0; n < 4; ++n)
          acc[m][n] = __builtin_amdgcn_mfma_f32_16x16x32_bf16(af[m], bfr[n],
                                                              acc[m][n], 0, 0, 0);
      __syncthreads();
    }

#pragma unroll
    for (int m = 0; m < 4; ++m) {
      int gr0 = rowBase + wm * 64 + m * 16 + lh * 4;
      int b = gr0 >> 9, nq0 = gr0 & 511;
#pragma unroll
      for (int n = 0; n < 4; ++n) {
        int gc = colBase + wn * 64 + n * 16 + lr;
        int hh = gc >> 6, d = gc & 63;
        size_t base = (((size_t)b * NH + hh) * NQ + nq0) * DH + d;
#pragma unroll
        for (int j = 0; j < 4; ++j)
          qbf[base + (size_t)j * DH] = f2bf(acc[m][n][j] * 0.125f);
      }
    }
  } else {
    // ---- gate GEMV: gv[b,h,nx] = xh[b,nx,:] . w_la[:,h] ----
    uint16_t* sW = smem;  // 16*1024
#pragma unroll
    for (int it = 0; it < 64; ++it) {
      int i = it * 256 + tid;
      int c = i >> 4, h = i & 15;
      sW[h * 1024 + (((c >> 3) ^ (h & 7)) << 3) + (c & 7)] = f2bf(wla[i]);
    }
    __syncthreads();

    const int rb = (blockIdx.x - 128) * 64 + wv * 16;
    f32x4 acc = {0.f, 0.f, 0.f, 0.f};
    for (int t = 0; t < 32; ++t) {
      bf16x8 af = *(const bf16x8*)&xh[(size_t)(rb + lr) * 1024 + t * 32 + lh * 8];
      bf16x8 bf = *(const bf16x8*)&sW[lr * 1024 + (((t * 4 + lh) ^ (lr & 7)) << 3)];
      acc = __builtin_amdgcn_mfma_f32_16x16x32_bf16(af, bf, acc, 0, 0, 0);
    }
    int nxg = rb + lh * 4;
    int b = nxg >> 11, nx = nxg & 2047;
    float4 st = {acc[0], acc[1], acc[2], acc[3]};
    *(float4*)&gv[((size_t)b * NH + lr) * NX + nx] = st;
  }
}

// ---------------- 8-phase 256x256 GEMM for x@w_kv (round-8 proven, 256 blocks = 1/CU) ----------------
// Race-free stage schedule (round-7 header): SA3(t+1)@q0, SB0(t+2)@q1,
// SB1(t+2)@q2, SA012(t+2)@q3; vmcnt(7)@q3 (counted, never 0 in loop).

__global__ __launch_bounds__(512, 2) void gemm_kv8(
    const uint16_t* __restrict__ A, const uint16_t* __restrict__ BT,
    uint16_t* __restrict__ outK, uint16_t* __restrict__ outV) {
  __shared__ __align__(16) uint16_t lds[65536];  // [buf][A|B][256][64]

  const int tid = threadIdx.x;
  const int wid = tid >> 6;
  const int lane = tid & 63;
  const int lr = lane & 15;
  const int lh = lane >> 4;
  const int wm = wid >> 2;
  const int wn = wid & 3;
  const int rowBase = blockIdx.x * 256;
  const int colBase = blockIdx.y * 256;

  f32x4 acc[8][4];
#pragma unroll
  for (int m = 0; m < 8; ++m)
#pragma unroll
    for (int n = 0; n < 4; ++n) acc[m][n] = (f32x4){0.f, 0.f, 0.f, 0.f};

  auto stageB = [&](int T, int h) {
    const uint16_t* srcp = BT + (size_t)(colBase + h * 128) * 1024 + T * 64;
    uint16_t* dst = lds + ((T & 1) * 32768 + 16384 + h * 8192);
#pragma unroll
    for (int it = 0; it < 2; ++it) {
      int s = it * 512 + tid;
      int row = s >> 3, cc = s & 7;
      int sc = cc ^ (row & 7);
      GLD16(srcp + (size_t)row * 1024 + sc * 8,
            dst + ((size_t)it * 512 + wid * 64) * 8);
    }
  };
  auto stageA012 = [&](int T) {
    const uint16_t* srcp = A + (size_t)rowBase * 1024 + T * 64;
    uint16_t* dstbase = lds + (T & 1) * 32768;
    int r64 = tid >> 3, cc = tid & 7;
#pragma unroll
    for (int st = 0; st < 3; ++st) {
      int rloc = (r64 < 32) ? (st * 32 + r64) : (96 + st * 32 + r64);
      int sc = cc ^ (rloc & 7);
      int wrow = (wid < 4) ? (st * 32 + wid * 8) : (128 + st * 32 + (wid - 4) * 8);
      GLD16(srcp + (size_t)rloc * 1024 + sc * 8, dstbase + (size_t)wrow * 64);
    }
  };
  auto stageA3 = [&](int T) {
    const uint16_t* srcp = A + (size_t)rowBase * 1024 + T * 64;
    uint16_t* dstbase = lds + (T & 1) * 32768;
    int r64 = tid >> 3, cc = tid & 7;
    int rloc = (r64 < 32) ? (96 + r64) : (192 + r64);
    int sc = cc ^ (rloc & 7);
    int wrow = (wid < 4) ? (96 + wid * 8) : (224 + (wid - 4) * 8);
    GLD16(srcp + (size_t)rloc * 1024 + sc * 8, dstbase + (size_t)wrow * 64);
  };

  auto rdA = [&](int p, int m, int kk) -> bf16x8 {
    int r = wm * 128 + m * 16 + lr;
    return *(const bf16x8*)&lds[p * 32768 + r * 64 +
                                (((kk * 4 + lh) ^ (r & 7)) << 3)];
  };
  auto rdB = [&](int p, int n, int kk) -> bf16x8 {
    int r = wn * 64 + n * 16 + lr;
    return *(const bf16x8*)&lds[p * 32768 + 16384 + r * 64 +
                                (((kk * 4 + lh) ^ (r & 7)) << 3)];
  };

  auto tile4 = [&](int t, bool last) {
    const int p = t & 1;
    bf16x8 b[4][2], a0[2], a1[2];
#pragma unroll
    for (int q = 0; q < 4; ++q) {
      if (q == 0) {
#pragma unroll
        for (int n = 0; n < 4; ++n)
#pragma unroll
          for (int kk = 0; kk < 2; ++kk) b[n][kk] = rdB(p, n, kk);
      }
#pragma unroll
      for (int kk = 0; kk < 2; ++kk) {
        a0[kk] = rdA(p, 2 * q, kk);
        a1[kk] = rdA(p, 2 * q + 1, kk);
      }
      if (q == 0) {
        stageA3(t + 1);
      } else if (q == 1) {
        if (!last) stageB(t + 2, 0);
      } else if (q == 2) {
        if (!last) stageB(t + 2, 1);
      } else {
        if (!last) stageA012(t + 2);
        if (last)
          asm volatile("s_waitcnt vmcnt(0)" ::: "memory");
        else
          asm volatile("s_waitcnt vmcnt(7)" ::: "memory");
      }
      __builtin_amdgcn_s_barrier();
      asm volatile("s_waitcnt lgkmcnt(0)" ::: "memory");
      __builtin_amdgcn_sched_barrier(0);
      __builtin_amdgcn_s_setprio(1);
#pragma unroll
      for (int n = 0; n < 4; ++n)
#pragma unroll
        for (int kk = 0; kk < 2; ++kk) {
          acc[2 * q][n] = __builtin_amdgcn_mfma_f32_16x16x32_bf16(
              a0[kk], b[n][kk], acc[2 * q][n], 0, 0, 0);
          acc[2 * q + 1][n] = __builtin_amdgcn_mfma_f32_16x16x32_bf16(
              a1[kk], b[n][kk], acc[2 * q + 1][n], 0, 0, 0);
        }
      __builtin_amdgcn_s_setprio(0);
      __builtin_amdgcn_s_barrier();
      asm volatile("" ::: "memory");
    }
  };

  auto tileEpi = [&](int t) {
    const int p = t & 1;
    bf16x8 b[4][2], a0[2], a1[2];
#pragma unroll
    for (int n = 0; n < 4; ++n)
#pragma unroll
      for (int kk = 0; kk < 2; ++kk) b[n][kk] = rdB(p, n, kk);
#pragma unroll
    for (int q = 0; q < 4; ++q) {
#pragma unroll
      for (int kk = 0; kk < 2; ++kk) {
        a0[kk] = rdA(p, 2 * q, kk);
        a1[kk] = rdA(p, 2 * q + 1, kk);
      }
#pragma unroll
      for (int n = 0; n < 4; ++n)
#pragma unroll
        for (int kk = 0; kk < 2; ++kk) {
          acc[2 * q][n] = __builtin_amdgcn_mfma_f32_16x16x32_bf16(
              a0[kk], b[n][kk], acc[2 * q][n], 0, 0, 0);
          acc[2 * q + 1][n] = __builtin_amdgcn_mfma_f32_16x16x32_bf16(
              a1[kk], b[n][kk], acc[2 * q + 1][n], 0, 0, 0);
        }
    }
  };

  stageB(0, 0); stageB(0, 1); stageA012(0); stageA3(0);
  stageB(1, 0); stageB(1, 1); stageA012(1);
  asm volatile("s_waitcnt vmcnt(7)" ::: "memory");
  __builtin_amdgcn_s_barrier();

  for (int t = 0; t < 14; ++t) tile4(t, false);
  tile4(14, true);
  tileEpi(15);

#pragma unroll
  for (int m = 0; m < 8; ++m) {
    int gr0 = rowBase + wm * 128 + m * 16 + lh * 4;
    int b_ = gr0 >> 11, nx0 = gr0 & 2047;
#pragma unroll
    for (int n = 0; n < 4; ++n) {
      int gc = colBase + wn * 64 + n * 16 + lr;
      if (gc < 1024) {
        int hh = gc >> 6, d = gc & 63;
        size_t base = (((size_t)b_ * NH + hh) * NX + nx0) * DH + d;
#pragma unroll
        for (int j = 0; j < 4; ++j)
          outK[base + (size_t)j * DH] = f2bf(acc[m][n][j]);
      } else {
        int c2 = gc - 1024;
        int hh = c2 >> 6, d = c2 & 63;
        ushort4 pv;
        pv.x = f2bf(acc[m][n][0]);
        pv.y = f2bf(acc[m][n][1]);
        pv.z = f2bf(acc[m][n][2]);
        pv.w = f2bf(acc[m][n][3]);
        *(ushort4*)&outV[(((size_t)b_ * NH + hh) * DH + d) * NX + nx0] = pv;
      }
    }
  }
}

// ---------------- 128x128 GEMM: ctx@w_proj + bias -> out fp32 ----------------

__global__ __launch_bounds__(256) void gemm_proj(
    const uint16_t* __restrict__ A, const uint16_t* __restrict__ BT,
    float* __restrict__ outF, const float* __restrict__ bias) {
  constexpr int K = 1024;
  __shared__ __align__(16) uint16_t sA[128 * 32];
  __shared__ __align__(16) uint16_t sB[128 * 32];

  const int tid = threadIdx.x;
  const int wv = tid >> 6;
  const int lane = tid & 63;
  const int lr = lane & 15;
  const int lh = lane >> 4;
  const int wm = wv >> 1, wn = wv & 1;
  const int rowBase = blockIdx.x * 128;
  const int colBase = blockIdx.y * 128;

  f32x4 zero4 = {0.f, 0.f, 0.f, 0.f};
  f32x4 acc[4][4];
#pragma unroll
  for (int m = 0; m < 4; ++m)
#pragma unroll
    for (int n = 0; n < 4; ++n) acc[m][n] = zero4;

  for (int k0 = 0; k0 < K; k0 += 32) {
#pragma unroll
    for (int it = 0; it < 2; ++it) {
      int s = it * 256 + tid;
      int row = s >> 2, cc = s & 3;
      int sc = cc ^ ((row >> 1) & 3);
      GLD16(A + (size_t)(rowBase + row) * K + k0 + sc * 8,
            sA + ((size_t)it * 256 + wv * 64) * 8);
      GLD16(BT + (size_t)(colBase + row) * K + k0 + sc * 8,
            sB + ((size_t)it * 256 + wv * 64) * 8);
    }
    __syncthreads();
    bf16x8 af[4], bfr[4];
#pragma unroll
    for (int m = 0; m < 4; ++m) {
      int r = wm * 64 + m * 16 + lr;
      af[m] = *(const bf16x8*)&sA[r * 32 + ((lh ^ ((r >> 1) & 3)) << 3)];
    }
#pragma unroll
    for (int n = 0; n < 4; ++n) {
      int r = wn * 64 + n * 16 + lr;
      bfr[n] = *(const bf16x8*)&sB[r * 32 + ((lh ^ ((r >> 1) & 3)) << 3)];
    }
#pragma unroll
    for (int m = 0; m < 4; ++m)
#pragma unroll
      for (int n = 0; n < 4; ++n)
        acc[m][n] = __builtin_amdgcn_mfma_f32_16x16x32_bf16(af[m], bfr[n],
                                                            acc[m][n], 0, 0, 0);
    __syncthreads();
  }

#pragma unroll
  for (int m = 0; m < 4; ++m) {
    int gr0 = rowBase + wm * 64 + m * 16 + lh * 4;
#pragma unroll
    for (int n = 0; n < 4; ++n) {
      int gc = colBase + wn * 64 + n * 16 + lr;
      float bi = bias[gc];
#pragma unroll
      for (int j = 0; j < 4; ++j)
        outF[(size_t)(gr0 + j) * 1024 + gc] = acc[m][n][j] + bi;
    }
  }
}

// ---------------- gate reduce ----------------

__global__ __launch_bounds__(256) void gate2_kernel(
    const float* __restrict__ gv, float* __restrict__ gate) {
  const int bh = blockIdx.x;
  const int tid = threadIdx.x;
  const float* p = gv + (size_t)bh * NX;
  float s = 0.f, mx = -1e30f;
  for (int i = tid; i < NX; i += 256) {
    float v = p[i];
    s += v;
    mx = fmaxf(mx, v);
  }
#pragma unroll
  for (int off = 1; off < 64; off <<= 1) {
    s += __shfl_xor(s, off, 64);
    mx = fmaxf(mx, __shfl_xor(mx, off, 64));
  }
  __shared__ float ss[4], sm[4];
  int wv = tid >> 6, lane = tid & 63;
  if (lane == 0) { ss[wv] = s; sm[wv] = mx; }
  __syncthreads();
  if (tid == 0) {
    float S = ss[0] + ss[1] + ss[2] + ss[3];
    float M = fmaxf(fmaxf(sm[0], sm[1]), fmaxf(sm[2], sm[3]));
    gate[bh] = 0.5f * (S / (float)NX) + 0.5f * M;
  }
}

// ---------------- column sum of V ----------------

__global__ __launch_bounds__(256) void vcolsum_kernel(
    const uint16_t* __restrict__ VT, float* __restrict__ vcs) {
  const int bh = blockIdx.x;
  const int wv = threadIdx.x >> 6, lane = threadIdx.x & 63;
#pragma unroll
  for (int dd = 0; dd < 4; ++dd) {
    int d = blockIdx.y * 16 + dd * 4 + wv;
    const uint16_t* row = VT + ((size_t)bh * DH + d) * NX;
    float s = 0.f;
#pragma unroll
    for (int i = 0; i < 4; ++i) {
      bf16x8 v = *(const bf16x8*)&row[(i * 64 + lane) * 8];
#pragma unroll
      for (int j = 0; j < 8; ++j) s += (float)v[j];
    }
#pragma unroll
    for (int off = 1; off < 64; off <<= 1) s += __shfl_xor(s, off, 64);
    if (lane == 0) vcs[bh * DH + d] = s;
  }
}

// ---------------- attention: single-pass flash, linearized softmax-2 (round-8 proven) ----------------

__global__ __launch_bounds__(256) void attn_kernel(
    const uint16_t* __restrict__ Q, const uint16_t* __restrict__ K,
    const uint16_t* __restrict__ VT, const float* __restrict__ gate,
    const float* __restrict__ attw, const float* __restrict__ vcs,
    uint16_t* __restrict__ ctxh) {
  __shared__ __align__(16) uint16_t sK[128 * 64];
  __shared__ __align__(16) uint16_t sV[64 * 128];
  __shared__ __align__(16) __bf16 sPe[64 * 128];

  const int tid = threadIdx.x;
  const int wv = tid >> 6;
  const int lane = tid & 63;
  const int lr = lane & 15;
  const int lh = lane >> 4;
  const int bh = blockIdx.x;
  const int q0 = blockIdx.y * 64;
  const float g = gate[bh];
  const float w = attw[0];

  const uint16_t* Qb = Q + ((size_t)bh * NQ + q0) * DH;
  const uint16_t* Kb = K + (size_t)bh * NX * DH;
  const uint16_t* Vb = VT + (size_t)bh * DH * NX;

  bf16x8 qa[2];
#pragma unroll
  for (int kk = 0; kk < 2; ++kk)
    qa[kk] = *(const bf16x8*)&Qb[(wv * 16 + lr) * DH + kk * 32 + lh * 8];

  float lp[4] = {0.f, 0.f, 0.f, 0.f};
  f32x4 zero4 = {0.f, 0.f, 0.f, 0.f};
  f32x4 accp[4];
#pragma unroll
  for (int d = 0; d < 4; ++d) accp[d] = zero4;

  for (int kt = 0; kt < 16; ++kt) {
#pragma unroll
    for (int it = 0; it < 4; ++it) {
      int s = it * 256 + tid;
      int row = s >> 3, cc = s & 7;
      int sc = cc ^ (row & 7);
      GLD16(Kb + (size_t)(kt * 128 + row) * DH + sc * 8,
            sK + ((size_t)it * 256 + wv * 64) * 8);
    }
#pragma unroll
    for (int it = 0; it < 4; ++it) {
      int s = it * 256 + tid;
      int row = s >> 4, cc = s & 15;
      int sc = cc ^ (row & 15);
      GLD16(Vb + (size_t)row * NX + kt * 128 + sc * 8,
            sV + ((size_t)it * 256 + wv * 64) * 8);
    }
    __syncthreads();
#pragma unroll
    for (int n = 0; n < 8; ++n) {
      f32x4 a4 = {0.f, 0.f, 0.f, 0.f};
      int r = n * 16 + lr;
#pragma unroll
      for (int kk = 0; kk < 2; ++kk) {
        bf16x8 kb = *(const bf16x8*)&sK[r * 64 + (((kk * 4 + lh) ^ (r & 7)) << 3)];
        a4 = __builtin_amdgcn_mfma_f32_16x16x32_bf16(qa[kk], kb, a4, 0, 0, 0);
      }
#pragma unroll
      for (int j = 0; j < 4; ++j) {
        float e = __expf(a4[j]);
        lp[j] += e;
        int qr = wv * 16 + lh * 4 + j;
        int key = n * 16 + lr;
        int idx = qr * 128 + ((((key >> 3) ^ (qr & 15))) << 3) + (key & 7);
        sPe[idx] = (__bf16)e;
      }
    }
    __syncthreads();
    const int prow = wv * 16 + lr;
#pragma unroll
    for (int kk = 0; kk < 4; ++kk) {
      int pidx = prow * 128 + (((kk * 4 + lh) ^ (prow & 15)) << 3);
      bf16x8 pe = *(const bf16x8*)&sPe[pidx];
#pragma unroll
      for (int df = 0; df < 4; ++df) {
        int vr = df * 16 + lr;
        bf16x8 vb = *(const bf16x8*)&sV[vr * 128 + (((kk * 4 + lh) ^ (vr & 15)) << 3)];
        accp[df] = __builtin_amdgcn_mfma_f32_16x16x32_bf16(pe, vb, accp[df], 0, 0, 0);
      }
    }
    __syncthreads();
  }
#pragma unroll
  for (int off = 1; off < 16; off <<= 1)
#pragma unroll
    for (int j = 0; j < 4; ++j) lp[j] += __shfl_xor(lp[j], off, 64);

  const int b = bh >> 4, h = bh & 15;
  const float c1 = w / ((float)NX + g);
  const float c2 = w * g / ((float)NX + g) + (1.f - w);
  float rl[4];
#pragma unroll
  for (int j = 0; j < 4; ++j) rl[j] = 1.f / lp[j];
#pragma unroll
  for (int df = 0; df < 4; ++df) {
    int d = df * 16 + lr;
    float cv = vcs[bh * DH + d];
#pragma unroll
    for (int j = 0; j < 4; ++j) {
      int qr = q0 + wv * 16 + lh * 4 + j;
      float p = accp[df][j] * rl[j];
      ctxh[(((size_t)b * NQ + qr) * NH + h) * DH + d] = f2bf(c1 * cv + c2 * p);
    }
  }
}

// ---------------- launch ----------------

extern "C" void kernel_launch(void* const* d_in, const int* in_sizes, int n_in,
                              void* d_out, int out_size, void* d_ws,
                              size_t ws_size, hipStream_t stream) {
  const float* x = (const float*)d_in[0];
  const float* cls = (const float*)d_in[1];
  const float* w_kv = (const float*)d_in[2];
  const float* w_q = (const float*)d_in[3];
  const float* w_la = (const float*)d_in[4];
  const float* w_proj = (const float*)d_in[5];
  const float* b_proj = (const float*)d_in[6];
  const float* att_w = (const float*)d_in[7];
  float* out = (float*)d_out;

  char* ws = (char*)d_ws;
  size_t off = 0;
  auto alloc = [&](size_t bytes) {
    void* p = ws + off;
    off += (bytes + 255) & ~(size_t)255;
    return p;
  };
  uint16_t* xh = (uint16_t*)alloc(4ull * NX * CDIM * 2);
  uint16_t* ch = (uint16_t*)alloc(4ull * NQ * CDIM * 2);
  uint16_t* wkvT = (uint16_t*)alloc(2048ull * 1024 * 2);
  uint16_t* wqT = (uint16_t*)alloc(1024ull * 1024 * 2);
  uint16_t* wpT = (uint16_t*)alloc(1024ull * 1024 * 2);
  uint16_t* kbf = (uint16_t*)alloc(4ull * NH * NX * DH * 2);
  uint16_t* vT = (uint16_t*)alloc(4ull * NH * DH * NX * 2);
  uint16_t* qbf = (uint16_t*)alloc(4ull * NH * NQ * DH * 2);
  float* gv = (float*)alloc(4ull * NH * NX * 4);
  float* gate = (float*)alloc(1024);
  float* vcs = (float*)alloc(4ull * NH * DH * 4);
  uint16_t* ctxh = (uint16_t*)alloc(4ull * NQ * CDIM * 2);

  cast2_bf16_kernel<<<2048, 256, 0, stream>>>(x, xh, 4 * NX * CDIM / 4,
                                              cls, ch, 4 * NQ * CDIM / 4);
  transT_all_kernel<<<dim3(32, 16, 3), 256, 0, stream>>>(w_kv, wkvT, w_q, wqT,
                                                         w_proj, wpT);

  aux_mm_kernel<<<256, 256, 0, stream>>>(ch, wqT, qbf, xh, w_la, gv);
  gemm_kv8<<<dim3(32, 8), 512, 0, stream>>>(xh, wkvT, kbf, vT);

  gate2_kernel<<<64, 256, 0, stream>>>(gv, gate);
  vcolsum_kernel<<<dim3(64, 4), 256, 0, stream>>>(vT, vcs);

  attn_kernel<<<dim3(64, 8), 256, 0, stream>>>(qbf, kbf, vT, gate, att_w, vcs, ctxh);

  gemm_proj<<<dim3(16, 8), 256, 0, stream>>>(ctxh, wpT, out, b_proj);
}